// Round 2
// baseline (187.317 us; speedup 1.0000x reference)
//
#include <hip/hip_runtime.h>
#include <hip/hip_bf16.h>

#define NB 64
#define NL 512
#define NH 768
#define NT 9

#define LOG2E 1.4426950408889634f
#define LN2   0.6931471805599453f
#define NEG_INF -1e30f

#if defined(__has_builtin)
#if __has_builtin(__builtin_amdgcn_exp2f)
#define EXP2F(x) __builtin_amdgcn_exp2f(x)
#else
#define EXP2F(x) exp2f(x)
#endif
#if __has_builtin(__builtin_amdgcn_logf)
#define LOG2F(x) __builtin_amdgcn_logf(x)
#else
#define LOG2F(x) log2f(x)
#endif
#else
#define EXP2F(x) exp2f(x)
#define LOG2F(x) log2f(x)
#endif

// ---------------------------------------------------------------------------
// Kernel A: logits = hidden @ W + b  ->  out+1   (also zeroes out[0] = loss)
// W staged in LDS as 4 sub-arrays by (k % 4), padded row stride 12 floats so
// each lane's 9-float column slice is two ds_read_b128 + one b32, and the
// lane-address stride (48B) avoids pathological bank conflicts.
// One wave per row: lane covers k = 4*(lane+64i)+m, butterfly-xor reduce.
// ---------------------------------------------------------------------------
__global__ __launch_bounds__(256) void gemm_kernel(
    const float* __restrict__ hidden, const float* __restrict__ W,
    const float* __restrict__ bias, float* __restrict__ out)
{
  __shared__ __align__(16) float w_lds[4 * 192 * 12];  // 9216 floats, 36.9 KB
  const int tid = threadIdx.x;
  for (int idx = tid; idx < NH * NT; idx += 256) {
    int k = idx / NT;
    int j = idx - k * NT;
    w_lds[(k & 3) * 2304 + (k >> 2) * 12 + j] = W[idx];
  }
  if (blockIdx.x == 0 && tid == 0) out[0] = 0.0f;
  __syncthreads();

  const int lane = tid & 63;
  const int wave = tid >> 6;
  const int gw = blockIdx.x * 4 + wave;  // 0..4095
  const float bj = (lane < NT) ? bias[lane] : 0.0f;

  for (int row = gw; row < NB * NL; row += 4096) {
    const float4* hp = reinterpret_cast<const float4*>(hidden + (size_t)row * NH);
    float acc[NT];
#pragma unroll
    for (int j = 0; j < NT; ++j) acc[j] = 0.0f;
#pragma unroll
    for (int i = 0; i < 3; ++i) {
      const int kk = lane + 64 * i;
      const float4 h4 = hp[kk];
#pragma unroll
      for (int m = 0; m < 4; ++m) {
        const float hh = (m == 0) ? h4.x : (m == 1) ? h4.y : (m == 2) ? h4.z : h4.w;
        const float* wl = &w_lds[m * 2304 + kk * 12];
        const float4 wa = *reinterpret_cast<const float4*>(wl);
        const float4 wb = *reinterpret_cast<const float4*>(wl + 4);
        const float w8 = wl[8];
        acc[0] = fmaf(hh, wa.x, acc[0]);
        acc[1] = fmaf(hh, wa.y, acc[1]);
        acc[2] = fmaf(hh, wa.z, acc[2]);
        acc[3] = fmaf(hh, wa.w, acc[3]);
        acc[4] = fmaf(hh, wb.x, acc[4]);
        acc[5] = fmaf(hh, wb.y, acc[5]);
        acc[6] = fmaf(hh, wb.z, acc[6]);
        acc[7] = fmaf(hh, wb.w, acc[7]);
        acc[8] = fmaf(hh, w8, acc[8]);
      }
    }
#pragma unroll
    for (int off = 32; off >= 1; off >>= 1) {
#pragma unroll
      for (int j = 0; j < NT; ++j) acc[j] += __shfl_xor(acc[j], off);
    }
    float v = acc[0];
#pragma unroll
    for (int j = 1; j < NT; ++j)
      if (lane == j) v = acc[j];
    if (lane < NT) out[1 + (size_t)row * NT + lane] = v + bj;
  }
}

// ---------------------------------------------------------------------------
// Kernel B: per-batch CRF NLL. One block per batch (576 threads).
//   stage: logits[b] (18KB), trans, E=exp(trans), mask into LDS
//   num:   gather + block reduce (threads 0..511)
//   phase1: 32 chunks x 16 steps; thread (c,i) folds row i of the running
//           chunk matrix; exp(trans) prefactored in 81 regs -> 9 exp + 81 fma
//           per fold instead of 81 exp.
//   phase2: wave 0 folds init-vector through the 32 chunk matrices (assoc.),
//           logsumexp with end_trans, atomicAdd(-llh/64) into out[0].
// ---------------------------------------------------------------------------
#define NC 32
#define CS 16

__global__ __launch_bounds__(576) void crf_kernel(
    const float* __restrict__ logits,  // out+1
    const int* __restrict__ mask, const int* __restrict__ labels,
    const float* __restrict__ start_trans, const float* __restrict__ end_trans,
    const float* __restrict__ trans, float* __restrict__ loss_out)
{
  const int b = blockIdx.x;
  const int tid = threadIdx.x;

  __shared__ float lg[NL * NT];       // 4608 floats
  __shared__ float trans_s[NT * NT];
  __shared__ float E_s[NT * NT];
  __shared__ int mask_s[NL];
  __shared__ float P[NC * NT * NT];   // 2592 floats
  __shared__ float red_num[9];
  __shared__ float red_cnt[9];

  const float* lgg = logits + (size_t)b * NL * NT;
  for (int idx = tid; idx < NL * NT; idx += 576) lg[idx] = lgg[idx];
  if (tid < NT * NT) {
    float tv = trans[tid];
    trans_s[tid] = tv;
    E_s[tid] = EXP2F(tv * LOG2E);
  }
  if (tid < NL) mask_s[tid] = mask[b * NL + tid];
  __syncthreads();

  // ---- numerator partials (threads 0..511 = timestep t) ----
  float numpart = 0.0f, cntpart = 0.0f;
  if (tid < NL) {
    int lab = labels[b * NL + tid];
    if (lab == -100) lab = 0;
    if (tid == 0) {
      numpart = start_trans[lab] + lg[lab];
    } else {
      int labp = labels[b * NL + tid - 1];
      if (labp == -100) labp = 0;
      float mf = (float)mask_s[tid];
      numpart = mf * (trans_s[labp * NT + lab] + lg[tid * NT + lab]);
    }
    cntpart = (float)mask_s[tid];
  }
#pragma unroll
  for (int off = 32; off >= 1; off >>= 1) {
    numpart += __shfl_down(numpart, off);
    cntpart += __shfl_down(cntpart, off);
  }
  if ((tid & 63) == 0) {
    red_num[tid >> 6] = numpart;
    red_cnt[tid >> 6] = cntpart;
  }

  // ---- phase 1: chunk matrix products ----
  if (tid < NC * NT) {
    const int c = tid / NT;
    const int i = tid - c * NT;
    float Er[NT * NT];
#pragma unroll
    for (int kj = 0; kj < NT * NT; ++kj) Er[kj] = E_s[kj];
    float run[NT];
    const int t0 = 1 + CS * c;
    if (mask_s[t0]) {
#pragma unroll
      for (int j = 0; j < NT; ++j) run[j] = trans_s[i * NT + j] + lg[t0 * NT + j];
    } else {
#pragma unroll
      for (int j = 0; j < NT; ++j) run[j] = (i == j) ? 0.0f : NEG_INF;
    }
    const int tend = min(t0 + CS, NL);
    for (int t = t0 + 1; t < tend; ++t) {
      if (!mask_s[t]) continue;
      float m = run[0];
#pragma unroll
      for (int k = 1; k < NT; ++k) m = fmaxf(m, run[k]);
      float p[NT];
#pragma unroll
      for (int k = 0; k < NT; ++k) p[k] = EXP2F((run[k] - m) * LOG2E);
      float dot[NT];
#pragma unroll
      for (int j = 0; j < NT; ++j) dot[j] = 0.0f;
#pragma unroll
      for (int k = 0; k < NT; ++k) {
#pragma unroll
        for (int j = 0; j < NT; ++j) dot[j] = fmaf(p[k], Er[k * NT + j], dot[j]);
      }
#pragma unroll
      for (int j = 0; j < NT; ++j)
        run[j] = fmaf(LOG2F(dot[j]), LN2, m) + lg[t * NT + j];
    }
#pragma unroll
    for (int j = 0; j < NT; ++j) P[c * (NT * NT) + i * NT + j] = run[j];
  }
  __syncthreads();

  // ---- phase 2: fold chunk matrices into init vector (wave 0 only) ----
  if (tid < 64) {
    const int j = tid;
    const int jj = (j < NT) ? j : 0;  // lanes >=9 compute harmless garbage
    float v = (j < NT) ? (start_trans[j] + lg[j]) : NEG_INF;
    for (int c = 0; c < NC; ++c) {
      float s[NT];
#pragma unroll
      for (int i = 0; i < NT; ++i)
        s[i] = __shfl(v, i) + P[c * (NT * NT) + i * NT + jj];
      float m = s[0];
#pragma unroll
      for (int i = 1; i < NT; ++i) m = fmaxf(m, s[i]);
      float sum = 0.0f;
#pragma unroll
      for (int i = 0; i < NT; ++i) sum += EXP2F((s[i] - m) * LOG2E);
      v = fmaf(LOG2F(sum), LN2, m);
    }
    float x = (j < NT) ? (v + end_trans[j]) : NEG_INF;
    float m = x;
#pragma unroll
    for (int off = 32; off >= 1; off >>= 1) m = fmaxf(m, __shfl_xor(m, off));
    float e = (j < NT) ? EXP2F((x - m) * LOG2E) : 0.0f;
#pragma unroll
    for (int off = 32; off >= 1; off >>= 1) e += __shfl_xor(e, off);
    if (tid == 0) {
      float denom = fmaf(LOG2F(e), LN2, m);
      float num = 0.0f, cnt = 0.0f;
#pragma unroll
      for (int w = 0; w < 9; ++w) {
        num += red_num[w];
        cnt += red_cnt[w];
      }
      int seq_end = (int)cnt - 1;
      int lastlab = labels[b * NL + seq_end];
      if (lastlab == -100) lastlab = 0;
      num += end_trans[lastlab];
      float llh = num - denom;
      atomicAdd(loss_out, -llh * (1.0f / NB));
    }
  }
}

extern "C" void kernel_launch(void* const* d_in, const int* in_sizes, int n_in,
                              void* d_out, int out_size, void* d_ws, size_t ws_size,
                              hipStream_t stream) {
  const float* hidden      = (const float*)d_in[0];
  const int*   attn_mask   = (const int*)d_in[1];
  const int*   labels      = (const int*)d_in[2];
  const float* W           = (const float*)d_in[3];
  const float* bias        = (const float*)d_in[4];
  const float* start_trans = (const float*)d_in[5];
  const float* end_trans   = (const float*)d_in[6];
  const float* trans       = (const float*)d_in[7];
  float* out = (float*)d_out;

  hipLaunchKernelGGL(gemm_kernel, dim3(1024), dim3(256), 0, stream,
                     hidden, W, bias, out);
  hipLaunchKernelGGL(crf_kernel, dim3(64), dim3(576), 0, stream,
                     out + 1, attn_mask, labels, start_trans, end_trans, trans, out);
}